// Round 3
// baseline (2108.938 us; speedup 1.0000x reference)
//
#include <hip/hip_runtime.h>
#include <stdint.h>

typedef __attribute__((ext_vector_type(8))) short s8v;
typedef __attribute__((ext_vector_type(4))) float f4v;

// ---- problem geometry ----
// x:(512,260) conv1-> h:(512,64,130) conv2-> z_e:(512,128,65)=z:(512,8320)
// codebook:(8192,8320); scores s_j = ||c_j||^2 - 2 z.c_j ; argmin
// outputs: emb[1], x_hat[512*260], mt[512*16], adv[512*16], perp[1]
#define OUT_XHAT 1
#define OUT_MT   133121
#define OUT_ADV  141313
#define OUT_PERP 149505

// ---- workspace layout (float offsets) ----
#define WS_COUNTS   0            // 8192
#define WS_EMB      8192         // 1 (+pad)
#define WS_A1       8256         // 131072
#define WS_CN       139328       // 8192  codebook row norms^2 (atomic)
#define WS_ZN2      147520       // 512   z row norms^2
#define WS_ZL1      148032       // 512   z row L1
#define WS_CBL1     148544       // 8192  (dump for cb L1)
#define WS_ZERO_N   156736
#define WS_ZE       156736       // 4,259,840  z_e
#define WS_SC0      4416576      // 4,194,304
#define WS_SC1      8610880      // 4,194,304
#define WS_ZQ       4416576      // 4,259,840 alias over SC0+SC1head (dead)
#define WS_HD       8676416      // 4,259,840 alias over SC1 tail (dead)
#define WS_W2T      12936256     // 32768
#define WS_WE       12969024     // 16384
#define WS_WO       12985408     // 16384
#define WS_W2TA     13001792     // 32768
#define WS_IDX      13034560     // 512 ints (+pad)
#define WS_ZPK      13035136     // 2,129,920 floats = 4,259,840 shorts
#define WS_CBT      15165056     // 34,078,720 floats = 68,157,440 shorts
#define WS_H        15165056     // h (conv1 out) inside cbt region, dead first
// total floats: 49,243,776  (~188 MB)

__device__ __forceinline__ short f2bf(float f) {
  uint32_t u = __float_as_uint(f);
  u = (u + 0x7FFFu + ((u >> 16) & 1u)) >> 16;  // RNE truncate to bf16
  return (short)u;
}

__device__ __forceinline__ void gl_lds16(const void* g, void* l) {
  __builtin_amdgcn_global_load_lds(
      (const __attribute__((address_space(1))) void*)g,
      (__attribute__((address_space(3))) void*)l, 16, 0, 0);
}

// ---------------- init / weight prep ----------------
__global__ void k_init(float* w) {
  int id = blockIdx.x * 256 + threadIdx.x;
  if (id < WS_ZERO_N) w[id] = 0.f;
}

__global__ void k_prep(const float* __restrict__ c2w, const float* __restrict__ d1w,
                       const float* __restrict__ aw2, float* __restrict__ w2t,
                       float* __restrict__ We, float* __restrict__ Wo,
                       float* __restrict__ w2ta) {
  int id = blockIdx.x * 256 + threadIdx.x;
  if (id < 32768) {
    int c = id & 127, ik = id >> 7;
    int i = ik >> 2, k = ik & 3;
    w2t[id] = c2w[(c * 64 + i) * 4 + k];     // w2t[(i*4+k)*128+c]
    int kk = id >> 7;
    w2ta[id] = aw2[(id & 127) * 256 + kk];   // w2ta[k*128+n]
  }
  if (id < 16384) {
    int o = id & 63, is = id >> 6;
    int i = is >> 1, s = is & 1;
    We[id] = d1w[(i * 64 + o) * 4 + (3 - 2 * s)];
    Wo[id] = d1w[(i * 64 + o) * 4 + (2 - 2 * s)];
  }
}

// ---------------- conv1 ----------------
__global__ void k_conv1(const float* __restrict__ x, const float* __restrict__ w,
                        const float* __restrict__ bias, float* __restrict__ h) {
  int id = blockIdx.x * 256 + threadIdx.x;
  if (id >= 512 * 64 * 130) return;
  int t = id % 130, bc = id / 130;
  int c = bc & 63, b = bc >> 6;
  const float* xb = x + b * 260;
  float acc = bias[c];
  int p0 = 2 * t - 1;
#pragma unroll
  for (int k = 0; k < 4; ++k) {
    int p = p0 + k;
    float xv = (p >= 0 && p < 260) ? xb[p] : 0.f;
    acc = fmaf(xv, w[c * 4 + k], acc);
  }
  h[id] = fmaxf(acc, 0.f);
}

// ---------------- generic gather-GEMM (conv2 / deconv1 even / odd) --------
template <int N>
__global__ __launch_bounds__(256) void k_gemm_gather(
    const float* __restrict__ src, int Cin, int Tsrc, int kdiv_shift,
    int tmul_shift, int toff, const float* __restrict__ wt,
    const float* __restrict__ bias, float* __restrict__ out, int out_cstride,
    int out_tmul, int out_toff, int do_relu) {
  const int NPT = N / 16;
  __shared__ float At[32 * 64];
  __shared__ float Bt[32 * N];
  int tid = threadIdx.x;
  int row0 = blockIdx.x * 64;
  int tm = (tid & 15) * 4;
  int tn = (tid >> 4) * NPT;
  int sr = tid & 63;
  int sj0 = (tid >> 6) * 8;
  int rowm = row0 + sr;
  int gb = rowm / 65;
  int gt = rowm - gb * 65;
  const float* sbase = src + (size_t)gb * Cin * Tsrc;
  int tpos = (gt << tmul_shift) + toff;
  int kmask = (1 << kdiv_shift) - 1;
  int bkr = tid >> 3;
  int bnc = (tid & 7) * (N / 8);

  float acc[4][NPT];
#pragma unroll
  for (int i = 0; i < 4; ++i)
#pragma unroll
    for (int j = 0; j < NPT; ++j) acc[i][j] = 0.f;

  for (int k0 = 0; k0 < 256; k0 += 32) {
    float av[8];
#pragma unroll
    for (int u = 0; u < 8; ++u) {
      int jj = k0 + sj0 + u;
      int cc = jj >> kdiv_shift;
      int kk = jj & kmask;
      int p = tpos + kk;
      av[u] = (p >= 0 && p < Tsrc) ? sbase[cc * Tsrc + p] : 0.f;
    }
    float bvv[N / 8];
#pragma unroll
    for (int u = 0; u < N / 8; ++u) bvv[u] = wt[(k0 + bkr) * N + bnc + u];
    __syncthreads();
#pragma unroll
    for (int u = 0; u < 8; ++u) At[(sj0 + u) * 64 + sr] = av[u];
#pragma unroll
    for (int u = 0; u < N / 8; ++u) Bt[bkr * N + bnc + u] = bvv[u];
    __syncthreads();
#pragma unroll
    for (int kk = 0; kk < 32; ++kk) {
      float a0 = At[kk * 64 + tm + 0];
      float a1 = At[kk * 64 + tm + 1];
      float a2 = At[kk * 64 + tm + 2];
      float a3 = At[kk * 64 + tm + 3];
#pragma unroll
      for (int j = 0; j < NPT; ++j) {
        float bv = Bt[kk * N + tn + j];
        acc[0][j] = fmaf(a0, bv, acc[0][j]);
        acc[1][j] = fmaf(a1, bv, acc[1][j]);
        acc[2][j] = fmaf(a2, bv, acc[2][j]);
        acc[3][j] = fmaf(a3, bv, acc[3][j]);
      }
    }
  }
#pragma unroll
  for (int i = 0; i < 4; ++i) {
    int rr = row0 + tm + i;
    int b = rr / 65, t = rr - b * 65;
#pragma unroll
    for (int j = 0; j < NPT; ++j) {
      int n = tn + j;
      float v = acc[i][j] + bias[n];
      if (do_relu) v = fmaxf(v, 0.f);
      out[(size_t)b * N * out_cstride + (size_t)n * out_cstride +
          t * out_tmul + out_toff] = v;
    }
  }
}

// ---------------- pack fp32 [R x 8320] -> bf16 k-chunk-major + norms ------
// dst[((k>>3)*R + r)*8 + (k&7)]; nrm2[r] += sum x^2 ; l1[r] += sum |x|
__global__ __launch_bounds__(256) void k_packmat(const float* __restrict__ src,
                                                 short* __restrict__ dst,
                                                 float* __restrict__ nrm2,
                                                 float* __restrict__ l1,
                                                 int R, int nb) {
  __shared__ short tile[8 * 64 * 8];
  __shared__ float rsq[256], rl1[256];
  int bid = blockIdx.x;
  int n0 = (bid % nb) * 64;
  int k0 = (bid / nb) * 64;
  int tid = threadIdx.x;
  int nr = tid >> 2, qc = tid & 3;
  const float* sp = src + (size_t)(n0 + nr) * 8320 + k0 + qc * 16;
  float v[16];
  *(float4*)&v[0] = *(const float4*)(sp);
  *(float4*)&v[4] = *(const float4*)(sp + 4);
  *(float4*)&v[8] = *(const float4*)(sp + 8);
  *(float4*)&v[12] = *(const float4*)(sp + 12);
  float sq = 0.f, sl = 0.f;
#pragma unroll
  for (int i = 0; i < 16; ++i) {
    sq = fmaf(v[i], v[i], sq);
    sl += fabsf(v[i]);
  }
  union { short s[8]; int4 q; } u0, u1;
#pragma unroll
  for (int j = 0; j < 8; ++j) {
    u0.s[j] = f2bf(v[j]);
    u1.s[j] = f2bf(v[8 + j]);
  }
  *(int4*)&tile[((qc * 2 + 0) * 64 + nr) * 8] = u0.q;
  *(int4*)&tile[((qc * 2 + 1) * 64 + nr) * 8] = u1.q;
  rsq[tid] = sq;
  rl1[tid] = sl;
  __syncthreads();
  if (tid < 64) {
    float s = rsq[tid * 4] + rsq[tid * 4 + 1] + rsq[tid * 4 + 2] + rsq[tid * 4 + 3];
    float t = rl1[tid * 4] + rl1[tid * 4 + 1] + rl1[tid * 4 + 2] + rl1[tid * 4 + 3];
    atomicAdd(&nrm2[n0 + tid], s);
    atomicAdd(&l1[n0 + tid], t);
  }
  int kc = tid >> 5, nn = (tid & 31) * 2;
  size_t ob = ((size_t)(k0 / 8 + kc) * R + n0 + nn) * 8;
  *(int4*)&dst[ob] = *(int4*)&tile[(kc * 64 + nn) * 8];
  *(int4*)&dst[ob + 8] = *(int4*)&tile[(kc * 64 + nn + 1) * 8];
}

// ---------------- scores GEMM: m97-style, 128x128 tile, BK=64, Ksplit=2 ---
__global__ __launch_bounds__(256) void k_scores(const short* __restrict__ cbt,
                                                const short* __restrict__ zpk,
                                                const float* __restrict__ cn,
                                                float* __restrict__ sc0,
                                                float* __restrict__ sc1) {
  __shared__ short As[8 * 128 * 8];  // 16 KB  [kc][m][8]
  __shared__ short Bs[8 * 128 * 8];  // 16 KB  [kc][n][8]
  int bid = blockIdx.x;
  int kh = bid & 1, nt = (bid >> 1) & 63, mt = bid >> 7;
  int tid = threadIdx.x;
  int wave = tid >> 6, lane = tid & 63;
  int q = lane >> 4, r16 = lane & 15;
  int m0 = mt * 128, n0 = nt * 128;
  int cb8 = kh * 520;
  int rb = (wave >> 1) * 64, cw = (wave & 1) * 64;

  f4v acc[4][4];
#pragma unroll
  for (int i = 0; i < 4; ++i)
#pragma unroll
    for (int j = 0; j < 4; ++j)
#pragma unroll
      for (int r = 0; r < 4; ++r) acc[i][j][r] = 0.f;

  for (int ks = 0; ks < 65; ++ks) {
    int c0 = cb8 + ks * 8;
    __syncthreads();
#pragma unroll
    for (int i = 0; i < 4; ++i) {
      int kc = wave * 2 + (i & 1);
      int h = (i >> 1) * 64;
      size_t gk = (size_t)(c0 + kc);
      gl_lds16(zpk + (gk * 512 + m0 + h + lane) * 8, &As[(kc * 128 + h) * 8]);
      gl_lds16(cbt + (gk * 8192 + n0 + h + lane) * 8, &Bs[(kc * 128 + h) * 8]);
    }
    __syncthreads();
    s8v af[2][4], bfr[2][4];
#pragma unroll
    for (int g = 0; g < 2; ++g) {
      int kq = (g * 4 + q) * 128;
#pragma unroll
      for (int i = 0; i < 4; ++i) {
        af[g][i] = *(const s8v*)&As[(kq + rb + i * 16 + r16) * 8];
        bfr[g][i] = *(const s8v*)&Bs[(kq + cw + i * 16 + r16) * 8];
      }
    }
#pragma unroll
    for (int g = 0; g < 2; ++g)
#pragma unroll
      for (int mi = 0; mi < 4; ++mi)
#pragma unroll
        for (int ni = 0; ni < 4; ++ni)
          acc[mi][ni] = __builtin_amdgcn_mfma_f32_16x16x32_bf16(
              af[g][mi], bfr[g][ni], acc[mi][ni], 0, 0, 0);
  }

  float* sc = kh ? sc1 : sc0;
#pragma unroll
  for (int mi = 0; mi < 4; ++mi) {
#pragma unroll
    for (int ni = 0; ni < 4; ++ni) {
      int col = n0 + cw + ni * 16 + r16;
      float cnv = kh ? 0.f : cn[col];
#pragma unroll
      for (int r = 0; r < 4; ++r) {
        int row = m0 + rb + mi * 16 + q * 4 + r;
        sc[(size_t)row * 8192 + col] = -2.f * acc[mi][ni][r] + cnv;
      }
    }
  }
}

// ---------------- argmin with exact fp32 recheck (wave-parallel) ----------
// Replicates the reference's rounding: d = fl(fl(zn+cn_j) - fl(2*dot_j)),
// quantized at ulp(~1330)=2^-13 -> quantized ties broken by smallest j.
__global__ void k_argmin(const float* __restrict__ s0, const float* __restrict__ s1,
                         const float* __restrict__ z_e, const float* __restrict__ cb,
                         const float* __restrict__ zl1, const float* __restrict__ zn2,
                         const float* __restrict__ cn, int* __restrict__ idx,
                         float* __restrict__ counts) {
  __shared__ float red[256];
  __shared__ int cand[128];
  __shared__ float cval[128];
  __shared__ int ccnt;
  int b = blockIdx.x, tid = threadIdx.x;
  const float* r0 = s0 + (size_t)b * 8192;
  const float* r1 = s1 + (size_t)b * 8192;
  float mn = 1e30f;
  for (int j = tid; j < 8192; j += 256) mn = fminf(mn, r0[j] + r1[j]);
  red[tid] = mn;
  __syncthreads();
  for (int st = 128; st > 0; st >>= 1) {
    if (tid < st) red[tid] = fminf(red[tid], red[tid + st]);
    __syncthreads();
  }
  float minv = red[0];
  // rigorous bound: 4*B1 + delta, B1 = 2^-8 * c_max * ||z||_1, delta=2^-13
  float margin = zl1[b] * (1.0f / 524288.0f) + 2e-4f;
  if (tid == 0) ccnt = 0;
  __syncthreads();
  for (int j = tid; j < 8192; j += 256) {
    float v = r0[j] + r1[j];
    if (v <= minv + margin) {
      int p = atomicAdd(&ccnt, 1);
      if (p < 128) cand[p] = j;
    }
  }
  __syncthreads();
  int nc = min(ccnt, 128);
  int wave = tid >> 6, lane = tid & 63;
  const float* zr = z_e + (size_t)b * 8320;
  float zn = zn2[b];
  for (int ci = wave; ci < nc; ci += 4) {
    int j = cand[ci];
    const float* cr = cb + (size_t)j * 8320;
    float dp = 0.f;
    for (int k = lane; k < 8320; k += 64) dp = fmaf(zr[k], cr[k], dp);
    for (int off = 32; off > 0; off >>= 1) dp += __shfl_down(dp, off);
    if (lane == 0)
      cval[ci] = __fsub_rn(__fadd_rn(zn, cn[j]), __fmul_rn(2.f, dp));
  }
  __syncthreads();
  if (tid == 0) {
    float bv = 1e30f;
    int bj = 0x7fffffff;
    for (int ci = 0; ci < nc; ++ci) {
      float v = cval[ci];
      int j = cand[ci];
      if (v < bv || (v == bv && j < bj)) { bv = v; bj = j; }
    }
    idx[b] = bj;
    atomicAdd(&counts[bj], 1.0f);
  }
}

// ---------------- gather zq + emb loss partial ----------------
__global__ void k_gather(const float* __restrict__ cb, const float* __restrict__ z_e,
                         const int* __restrict__ idx, float* __restrict__ zq,
                         float* __restrict__ emb_acc) {
  __shared__ float red[256];
  int b = blockIdx.x, tid = threadIdx.x;
  int j = idx[b];
  const float* cr = cb + (size_t)j * 8320;
  const float* zr = z_e + (size_t)b * 8320;
  float* q = zq + (size_t)b * 8320;
  float part = 0.f;
  for (int k = tid; k < 8320; k += 256) {
    float c = cr[k];
    float d = c - zr[k];
    q[k] = c;
    part += d * d;
  }
  red[tid] = part;
  __syncthreads();
  for (int st = 128; st > 0; st >>= 1) {
    if (tid < st) red[tid] += red[tid + st];
    __syncthreads();
  }
  if (tid == 0) atomicAdd(emb_acc, red[0]);
}

// ---------------- deconv2 -> x_hat ----------------
__global__ void k_dec2(const float* __restrict__ hd, const float* __restrict__ w,
                       const float* __restrict__ bias, float* __restrict__ out) {
  int id = blockIdx.x * 256 + threadIdx.x;
  if (id >= 512 * 260) return;
  int b = id / 260, t = id % 260;
  int u = t >> 1;
  const float* hb = hd + (size_t)b * 8320;
  float acc = bias[0];
  if (t & 1) {
    bool ok = (u + 1 < 130);
    for (int i = 0; i < 64; ++i) {
      acc = fmaf(hb[i * 130 + u], w[i * 4 + 2], acc);
      if (ok) acc = fmaf(hb[i * 130 + u + 1], w[i * 4 + 0], acc);
    }
  } else {
    bool ok = (u >= 1);
    for (int i = 0; i < 64; ++i) {
      if (ok) acc = fmaf(hb[i * 130 + u - 1], w[i * 4 + 3], acc);
      acc = fmaf(hb[i * 130 + u], w[i * 4 + 1], acc);
    }
  }
  out[OUT_XHAT + id] = acc;
}

// ---------------- mt head (float4 loads) ----------------
__global__ void k_mt(const float* __restrict__ z_e, const float* __restrict__ mtw,
                     const float* __restrict__ mtb, float* __restrict__ out) {
  __shared__ float red[64];
  int b = blockIdx.x, tid = threadIdx.x;
  int wave = tid >> 6, lane = tid & 63;
  const float* zr = z_e + (size_t)b * 8320;
  float acc[16];
#pragma unroll
  for (int n = 0; n < 16; ++n) acc[n] = 0.f;
  for (int k4 = tid; k4 < 1040; k4 += 256) {
    float4 zv = *(const float4*)&zr[k4 * 4];
#pragma unroll
    for (int n = 0; n < 16; ++n) {
      float4 wv = *(const float4*)&mtw[n * 4160 + k4 * 4];
      float a = acc[n];
      a = fmaf(zv.x, wv.x, a);
      a = fmaf(zv.y, wv.y, a);
      a = fmaf(zv.z, wv.z, a);
      a = fmaf(zv.w, wv.w, a);
      acc[n] = a;
    }
  }
#pragma unroll
  for (int n = 0; n < 16; ++n) {
    float v = acc[n];
    for (int off = 32; off > 0; off >>= 1) v += __shfl_down(v, off);
    if (lane == 0) red[n * 4 + wave] = v;
  }
  __syncthreads();
  if (tid < 16) {
    float s = red[tid * 4] + red[tid * 4 + 1] + red[tid * 4 + 2] + red[tid * 4 + 3];
    out[OUT_MT + b * 16 + tid] = s + mtb[tid];
  }
}

// ---------------- adv layer 1 (tiled fp32 GEMM, K-split 10, atomic acc) ----
__global__ __launch_bounds__(256) void k_adv1(const float* __restrict__ z_e,
                                              const float* __restrict__ w1,
                                              float* __restrict__ a1) {
  __shared__ float At[32 * 64];
  __shared__ float Bt[32 * 64];
  int bid = blockIdx.x;
  int ksp = bid % 10;
  int nt = (bid / 10) & 3;
  int mt = bid / 40;
  int tid = threadIdx.x;
  int m0 = mt * 64, n0 = nt * 64, kb = ksp * 416;
  int tm = (tid & 15) * 4, tn = (tid >> 4) * 4;
  int sr = tid & 63, sj = (tid >> 6) * 8;
  const float* za = z_e + (size_t)(m0 + sr) * 8320 + 4160 + kb + sj;
  const float* wb = w1 + (size_t)(n0 + sr) * 4160 + kb + sj;
  float acc[4][4];
#pragma unroll
  for (int i = 0; i < 4; ++i)
#pragma unroll
    for (int j = 0; j < 4; ++j) acc[i][j] = 0.f;
  for (int k0 = 0; k0 < 416; k0 += 32) {
    float4 av0 = *(const float4*)(za + k0);
    float4 av1 = *(const float4*)(za + k0 + 4);
    float4 bv0 = *(const float4*)(wb + k0);
    float4 bv1 = *(const float4*)(wb + k0 + 4);
    __syncthreads();
    At[(sj + 0) * 64 + sr] = av0.x; At[(sj + 1) * 64 + sr] = av0.y;
    At[(sj + 2) * 64 + sr] = av0.z; At[(sj + 3) * 64 + sr] = av0.w;
    At[(sj + 4) * 64 + sr] = av1.x; At[(sj + 5) * 64 + sr] = av1.y;
    At[(sj + 6) * 64 + sr] = av1.z; At[(sj + 7) * 64 + sr] = av1.w;
    Bt[(sj + 0) * 64 + sr] = bv0.x; Bt[(sj + 1) * 64 + sr] = bv0.y;
    Bt[(sj + 2) * 64 + sr] = bv0.z; Bt[(sj + 3) * 64 + sr] = bv0.w;
    Bt[(sj + 4) * 64 + sr] = bv1.x; Bt[(sj + 5) * 64 + sr] = bv1.y;
    Bt[(sj + 6) * 64 + sr] = bv1.z; Bt[(sj + 7) * 64 + sr] = bv1.w;
    __syncthreads();
#pragma unroll
    for (int kk = 0; kk < 32; ++kk) {
      float4 aa = *(const float4*)&At[kk * 64 + tm];
      float4 bb = *(const float4*)&Bt[kk * 64 + tn];
      acc[0][0] = fmaf(aa.x, bb.x, acc[0][0]); acc[0][1] = fmaf(aa.x, bb.y, acc[0][1]);
      acc[0][2] = fmaf(aa.x, bb.z, acc[0][2]); acc[0][3] = fmaf(aa.x, bb.w, acc[0][3]);
      acc[1][0] = fmaf(aa.y, bb.x, acc[1][0]); acc[1][1] = fmaf(aa.y, bb.y, acc[1][1]);
      acc[1][2] = fmaf(aa.y, bb.z, acc[1][2]); acc[1][3] = fmaf(aa.y, bb.w, acc[1][3]);
      acc[2][0] = fmaf(aa.z, bb.x, acc[2][0]); acc[2][1] = fmaf(aa.z, bb.y, acc[2][1]);
      acc[2][2] = fmaf(aa.z, bb.z, acc[2][2]); acc[2][3] = fmaf(aa.z, bb.w, acc[2][3]);
      acc[3][0] = fmaf(aa.w, bb.x, acc[3][0]); acc[3][1] = fmaf(aa.w, bb.y, acc[3][1]);
      acc[3][2] = fmaf(aa.w, bb.z, acc[3][2]); acc[3][3] = fmaf(aa.w, bb.w, acc[3][3]);
    }
  }
#pragma unroll
  for (int i = 0; i < 4; ++i)
#pragma unroll
    for (int j = 0; j < 4; ++j)
      atomicAdd(&a1[(size_t)(m0 + tm + i) * 256 + n0 + tn + j], acc[i][j]);
}

// ---------------- adv layers 2+3 fused ----------------
__global__ void k_adv23(const float* __restrict__ a1raw, const float* __restrict__ b1,
                        const float* __restrict__ w2t, const float* __restrict__ b2,
                        const float* __restrict__ w3, const float* __restrict__ b3,
                        float* __restrict__ out) {
  __shared__ float s1[256];
  __shared__ float s2[128];
  int b = blockIdx.x, tid = threadIdx.x;
  s1[tid] = fmaxf(a1raw[(size_t)b * 256 + tid] + b1[tid], 0.f);
  __syncthreads();
  if (tid < 128) {
    float acc = b2[tid];
    for (int k = 0; k < 256; ++k) acc = fmaf(s1[k], w2t[k * 128 + tid], acc);
    s2[tid] = fmaxf(acc, 0.f);
  }
  __syncthreads();
  if (tid < 16) {
    float acc = b3[tid];
    for (int k = 0; k < 128; ++k) acc = fmaf(s2[k], w3[tid * 128 + k], acc);
    out[OUT_ADV + b * 16 + tid] = acc;
  }
}

// ---------------- finalize: emb loss + perplexity ----------------
__global__ void k_fin(const float* __restrict__ counts, const float* __restrict__ emb_acc,
                      const float* __restrict__ beta_p, float* __restrict__ out) {
  __shared__ float red[256];
  int tid = threadIdx.x;
  float part = 0.f;
  for (int j = tid; j < 8192; j += 256) {
    float e = counts[j] * (1.0f / 512.0f);
    part += e * logf(e + 1e-10f);
  }
  red[tid] = part;
  __syncthreads();
  for (int st = 128; st > 0; st >>= 1) {
    if (tid < st) red[tid] += red[tid + st];
    __syncthreads();
  }
  if (tid == 0) {
    out[OUT_PERP] = expf(-red[0]);
    out[0] = (1.f + beta_p[0]) * emb_acc[0] * (1.0f / 4259840.0f);
  }
}

extern "C" void kernel_launch(void* const* d_in, const int* in_sizes, int n_in,
                              void* d_out, int out_size, void* d_ws, size_t ws_size,
                              hipStream_t stream) {
  (void)in_sizes; (void)n_in; (void)out_size; (void)ws_size;
  const float* x   = (const float*)d_in[0];
  const float* cb  = (const float*)d_in[1];
  const float* c1w = (const float*)d_in[2];
  const float* c1b = (const float*)d_in[3];
  const float* c2w = (const float*)d_in[4];
  const float* c2b = (const float*)d_in[5];
  const float* d1w = (const float*)d_in[6];
  const float* d1b = (const float*)d_in[7];
  const float* d2w = (const float*)d_in[8];
  const float* d2b = (const float*)d_in[9];
  const float* mtw = (const float*)d_in[10];
  const float* mtb = (const float*)d_in[11];
  const float* aw1 = (const float*)d_in[12];
  const float* ab1 = (const float*)d_in[13];
  const float* aw2 = (const float*)d_in[14];
  const float* ab2 = (const float*)d_in[15];
  const float* aw3 = (const float*)d_in[16];
  const float* ab3 = (const float*)d_in[17];
  const float* beta = (const float*)d_in[18];
  float* out = (float*)d_out;
  float* W = (float*)d_ws;

  float* counts = W + WS_COUNTS;
  float* embac  = W + WS_EMB;
  float* a1buf  = W + WS_A1;
  float* cnbuf  = W + WS_CN;
  float* zn2    = W + WS_ZN2;
  float* zl1    = W + WS_ZL1;
  float* cbl1   = W + WS_CBL1;
  float* zebuf  = W + WS_ZE;
  float* sc0    = W + WS_SC0;
  float* sc1    = W + WS_SC1;
  float* zqbuf  = W + WS_ZQ;
  float* hdbuf  = W + WS_HD;
  float* w2t    = W + WS_W2T;
  float* We     = W + WS_WE;
  float* Wo     = W + WS_WO;
  float* w2ta   = W + WS_W2TA;
  int*   idxb   = (int*)(W + WS_IDX);
  short* zpk    = (short*)(W + WS_ZPK);
  short* cbt    = (short*)(W + WS_CBT);
  float* hbuf   = W + WS_H;   // aliases cbt region; dead before cbt written

  k_init<<<(WS_ZERO_N + 255) / 256, 256, 0, stream>>>(W);
  k_prep<<<128, 256, 0, stream>>>(c2w, d1w, aw2, w2t, We, Wo, w2ta);
  k_conv1<<<16640, 256, 0, stream>>>(x, c1w, c1b, hbuf);
  k_gemm_gather<128><<<520, 256, 0, stream>>>(hbuf, 64, 130, 2, 1, -1, w2t, c2b,
                                              zebuf, 65, 1, 0, 0);
  // pack z -> bf16 chunk-major + ||z||^2 + ||z||_1   (h now dead)
  k_packmat<<<8 * 130, 256, 0, stream>>>(zebuf, zpk, zn2, zl1, 512, 8);
  // pack codebook -> bf16 chunk-major + ||c||^2  (overwrites h region)
  k_packmat<<<128 * 130, 256, 0, stream>>>(cb, cbt, cnbuf, cbl1, 8192, 128);
  k_scores<<<512, 256, 0, stream>>>(cbt, zpk, cnbuf, sc0, sc1);
  k_argmin<<<512, 256, 0, stream>>>(sc0, sc1, zebuf, cb, zl1, zn2, cnbuf, idxb,
                                    counts);
  k_gather<<<512, 256, 0, stream>>>(cb, zebuf, idxb, zqbuf, embac);
  k_gemm_gather<64><<<520, 256, 0, stream>>>(zqbuf, 128, 65, 1, 0, -1, We, d1b,
                                             hdbuf, 130, 2, 0, 1);
  k_gemm_gather<64><<<520, 256, 0, stream>>>(zqbuf, 128, 65, 1, 0, 0, Wo, d1b,
                                             hdbuf, 130, 2, 1, 1);
  k_dec2<<<520, 256, 0, stream>>>(hdbuf, d2w, d2b, out);
  k_mt<<<512, 256, 0, stream>>>(zebuf, mtw, mtb, out);
  k_adv1<<<320, 256, 0, stream>>>(zebuf, aw1, a1buf);
  k_adv23<<<512, 256, 0, stream>>>(a1buf, ab1, w2ta, ab2, aw3, ab3, out);
  k_fin<<<1, 256, 0, stream>>>(counts, embac, beta, out);
}

// Round 4
// 846.606 us; speedup vs baseline: 2.4910x; 2.4910x over previous
//
#include <hip/hip_runtime.h>
#include <stdint.h>

typedef __attribute__((ext_vector_type(8))) short s8v;
typedef __attribute__((ext_vector_type(4))) float f4v;

// ---- problem geometry ----
// x:(512,260) conv1-> h:(512,64,130) conv2-> z_e:(512,128,65)=z:(512,8320)
// codebook:(8192,8320); scores s_j = ||c_j||^2 - 2 z.c_j ; argmin
// outputs: emb[1], x_hat[512*260], mt[512*16], adv[512*16], perp[1]
#define OUT_XHAT 1
#define OUT_MT   133121
#define OUT_ADV  141313
#define OUT_PERP 149505

// ---- workspace layout (float offsets) ----
#define WS_COUNTS   0            // 8192
#define WS_EMB      8192         // 1 (+pad)
#define WS_A1       8256         // 131072
#define WS_CN       139328       // 8192  codebook row norms^2 (atomic)
#define WS_ZN2      147520       // 512   z row norms^2
#define WS_ZL1      148032       // 512   z row L1
#define WS_CBL1     148544       // 8192  (dump for cb L1)
#define WS_ZERO_N   156736
#define WS_ZE       156736       // 4,259,840  z_e
#define WS_SC0      4416576      // 4,194,304
#define WS_SC1      8610880      // 4,194,304
#define WS_ZQ       4416576      // 4,259,840 alias over SC0+SC1head (dead)
#define WS_HD       8676416      // 4,259,840 alias over SC1 tail (dead)
#define WS_W2T      12936256     // 32768
#define WS_WE       12969024     // 16384
#define WS_WO       12985408     // 16384
#define WS_W2TA     13001792     // 32768
#define WS_IDX      13034560     // 512 ints (+pad)
#define WS_ZPK      13035136     // 2,129,920 floats = 4,259,840 shorts
#define WS_CBT      15165056     // 34,078,720 floats = 68,157,440 shorts
#define WS_H        15165056     // h (conv1 out) inside cbt region, dead first
// total floats: 49,243,776  (~188 MB)

__device__ __forceinline__ short f2bf(float f) {
  uint32_t u = __float_as_uint(f);
  u = (u + 0x7FFFu + ((u >> 16) & 1u)) >> 16;  // RNE truncate to bf16
  return (short)u;
}

__device__ __forceinline__ void gl_lds16(const void* g, void* l) {
  __builtin_amdgcn_global_load_lds(
      (const __attribute__((address_space(1))) void*)g,
      (__attribute__((address_space(3))) void*)l, 16, 0, 0);
}

// ---------------- init / weight prep ----------------
__global__ void k_init(float* w) {
  int id = blockIdx.x * 256 + threadIdx.x;
  if (id < WS_ZERO_N) w[id] = 0.f;
}

__global__ void k_prep(const float* __restrict__ c2w, const float* __restrict__ d1w,
                       const float* __restrict__ aw2, float* __restrict__ w2t,
                       float* __restrict__ We, float* __restrict__ Wo,
                       float* __restrict__ w2ta) {
  int id = blockIdx.x * 256 + threadIdx.x;
  if (id < 32768) {
    int c = id & 127, ik = id >> 7;
    int i = ik >> 2, k = ik & 3;
    w2t[id] = c2w[(c * 64 + i) * 4 + k];     // w2t[(i*4+k)*128+c]
    int kk = id >> 7;
    w2ta[id] = aw2[(id & 127) * 256 + kk];   // w2ta[k*128+n]
  }
  if (id < 16384) {
    int o = id & 63, is = id >> 6;
    int i = is >> 1, s = is & 1;
    We[id] = d1w[(i * 64 + o) * 4 + (3 - 2 * s)];
    Wo[id] = d1w[(i * 64 + o) * 4 + (2 - 2 * s)];
  }
}

// ---------------- conv1 ----------------
__global__ void k_conv1(const float* __restrict__ x, const float* __restrict__ w,
                        const float* __restrict__ bias, float* __restrict__ h) {
  int id = blockIdx.x * 256 + threadIdx.x;
  if (id >= 512 * 64 * 130) return;
  int t = id % 130, bc = id / 130;
  int c = bc & 63, b = bc >> 6;
  const float* xb = x + b * 260;
  float acc = bias[c];
  int p0 = 2 * t - 1;
#pragma unroll
  for (int k = 0; k < 4; ++k) {
    int p = p0 + k;
    float xv = (p >= 0 && p < 260) ? xb[p] : 0.f;
    acc = fmaf(xv, w[c * 4 + k], acc);
  }
  h[id] = fmaxf(acc, 0.f);
}

// ---------------- generic gather-GEMM (conv2 / deconv1 even / odd) --------
template <int N>
__global__ __launch_bounds__(256) void k_gemm_gather(
    const float* __restrict__ src, int Cin, int Tsrc, int kdiv_shift,
    int tmul_shift, int toff, const float* __restrict__ wt,
    const float* __restrict__ bias, float* __restrict__ out, int out_cstride,
    int out_tmul, int out_toff, int do_relu) {
  const int NPT = N / 16;
  __shared__ float At[32 * 64];
  __shared__ float Bt[32 * N];
  int tid = threadIdx.x;
  int row0 = blockIdx.x * 64;
  int tm = (tid & 15) * 4;
  int tn = (tid >> 4) * NPT;
  int sr = tid & 63;
  int sj0 = (tid >> 6) * 8;
  int rowm = row0 + sr;
  int gb = rowm / 65;
  int gt = rowm - gb * 65;
  const float* sbase = src + (size_t)gb * Cin * Tsrc;
  int tpos = (gt << tmul_shift) + toff;
  int kmask = (1 << kdiv_shift) - 1;
  int bkr = tid >> 3;
  int bnc = (tid & 7) * (N / 8);

  float acc[4][NPT];
#pragma unroll
  for (int i = 0; i < 4; ++i)
#pragma unroll
    for (int j = 0; j < NPT; ++j) acc[i][j] = 0.f;

  for (int k0 = 0; k0 < 256; k0 += 32) {
    float av[8];
#pragma unroll
    for (int u = 0; u < 8; ++u) {
      int jj = k0 + sj0 + u;
      int cc = jj >> kdiv_shift;
      int kk = jj & kmask;
      int p = tpos + kk;
      av[u] = (p >= 0 && p < Tsrc) ? sbase[cc * Tsrc + p] : 0.f;
    }
    float bvv[N / 8];
#pragma unroll
    for (int u = 0; u < N / 8; ++u) bvv[u] = wt[(k0 + bkr) * N + bnc + u];
    __syncthreads();
#pragma unroll
    for (int u = 0; u < 8; ++u) At[(sj0 + u) * 64 + sr] = av[u];
#pragma unroll
    for (int u = 0; u < N / 8; ++u) Bt[bkr * N + bnc + u] = bvv[u];
    __syncthreads();
#pragma unroll
    for (int kk = 0; kk < 32; ++kk) {
      float a0 = At[kk * 64 + tm + 0];
      float a1 = At[kk * 64 + tm + 1];
      float a2 = At[kk * 64 + tm + 2];
      float a3 = At[kk * 64 + tm + 3];
#pragma unroll
      for (int j = 0; j < NPT; ++j) {
        float bv = Bt[kk * N + tn + j];
        acc[0][j] = fmaf(a0, bv, acc[0][j]);
        acc[1][j] = fmaf(a1, bv, acc[1][j]);
        acc[2][j] = fmaf(a2, bv, acc[2][j]);
        acc[3][j] = fmaf(a3, bv, acc[3][j]);
      }
    }
  }
#pragma unroll
  for (int i = 0; i < 4; ++i) {
    int rr = row0 + tm + i;
    int b = rr / 65, t = rr - b * 65;
#pragma unroll
    for (int j = 0; j < NPT; ++j) {
      int n = tn + j;
      float v = acc[i][j] + bias[n];
      if (do_relu) v = fmaxf(v, 0.f);
      out[(size_t)b * N * out_cstride + (size_t)n * out_cstride +
          t * out_tmul + out_toff] = v;
    }
  }
}

// ---------------- pack fp32 [R x 8320] -> bf16 k-chunk-major + norms ------
// dst[((k>>3)*R + r)*8 + (k&7)]; nrm2[r] += sum x^2 ; l1[r] += sum |x|
__global__ __launch_bounds__(256) void k_packmat(const float* __restrict__ src,
                                                 short* __restrict__ dst,
                                                 float* __restrict__ nrm2,
                                                 float* __restrict__ l1,
                                                 int R, int nb) {
  __shared__ short tile[8 * 64 * 8];
  __shared__ float rsq[256], rl1[256];
  int bid = blockIdx.x;
  int n0 = (bid % nb) * 64;
  int k0 = (bid / nb) * 64;
  int tid = threadIdx.x;
  int nr = tid >> 2, qc = tid & 3;
  const float* sp = src + (size_t)(n0 + nr) * 8320 + k0 + qc * 16;
  float v[16];
  *(float4*)&v[0] = *(const float4*)(sp);
  *(float4*)&v[4] = *(const float4*)(sp + 4);
  *(float4*)&v[8] = *(const float4*)(sp + 8);
  *(float4*)&v[12] = *(const float4*)(sp + 12);
  float sq = 0.f, sl = 0.f;
#pragma unroll
  for (int i = 0; i < 16; ++i) {
    sq = fmaf(v[i], v[i], sq);
    sl += fabsf(v[i]);
  }
  union { short s[8]; int4 q; } u0, u1;
#pragma unroll
  for (int j = 0; j < 8; ++j) {
    u0.s[j] = f2bf(v[j]);
    u1.s[j] = f2bf(v[8 + j]);
  }
  *(int4*)&tile[((qc * 2 + 0) * 64 + nr) * 8] = u0.q;
  *(int4*)&tile[((qc * 2 + 1) * 64 + nr) * 8] = u1.q;
  rsq[tid] = sq;
  rl1[tid] = sl;
  __syncthreads();
  if (tid < 64) {
    float s = rsq[tid * 4] + rsq[tid * 4 + 1] + rsq[tid * 4 + 2] + rsq[tid * 4 + 3];
    float t = rl1[tid * 4] + rl1[tid * 4 + 1] + rl1[tid * 4 + 2] + rl1[tid * 4 + 3];
    atomicAdd(&nrm2[n0 + tid], s);
    atomicAdd(&l1[n0 + tid], t);
  }
  int kc = tid >> 5, nn = (tid & 31) * 2;
  size_t ob = ((size_t)(k0 / 8 + kc) * R + n0 + nn) * 8;
  *(int4*)&dst[ob] = *(int4*)&tile[(kc * 64 + nn) * 8];
  *(int4*)&dst[ob + 8] = *(int4*)&tile[(kc * 64 + nn + 1) * 8];
}

// ---------------- scores GEMM: m97-style, 128x128 tile, BK=64, Ksplit=2 ---
__global__ __launch_bounds__(256) void k_scores(const short* __restrict__ cbt,
                                                const short* __restrict__ zpk,
                                                const float* __restrict__ cn,
                                                float* __restrict__ sc0,
                                                float* __restrict__ sc1) {
  __shared__ short As[8 * 128 * 8];  // 16 KB  [kc][m][8]
  __shared__ short Bs[8 * 128 * 8];  // 16 KB  [kc][n][8]
  int bid = blockIdx.x;
  int kh = bid & 1, nt = (bid >> 1) & 63, mt = bid >> 7;
  int tid = threadIdx.x;
  int wave = tid >> 6, lane = tid & 63;
  int q = lane >> 4, r16 = lane & 15;
  int m0 = mt * 128, n0 = nt * 128;
  int cb8 = kh * 520;
  int rb = (wave >> 1) * 64, cw = (wave & 1) * 64;

  f4v acc[4][4];
#pragma unroll
  for (int i = 0; i < 4; ++i)
#pragma unroll
    for (int j = 0; j < 4; ++j)
#pragma unroll
      for (int r = 0; r < 4; ++r) acc[i][j][r] = 0.f;

  for (int ks = 0; ks < 65; ++ks) {
    int c0 = cb8 + ks * 8;
    __syncthreads();
#pragma unroll
    for (int i = 0; i < 4; ++i) {
      int kc = wave * 2 + (i & 1);
      int h = (i >> 1) * 64;
      size_t gk = (size_t)(c0 + kc);
      gl_lds16(zpk + (gk * 512 + m0 + h + lane) * 8, &As[(kc * 128 + h) * 8]);
      gl_lds16(cbt + (gk * 8192 + n0 + h + lane) * 8, &Bs[(kc * 128 + h) * 8]);
    }
    __syncthreads();
    s8v af[2][4], bfr[2][4];
#pragma unroll
    for (int g = 0; g < 2; ++g) {
      int kq = (g * 4 + q) * 128;
#pragma unroll
      for (int i = 0; i < 4; ++i) {
        af[g][i] = *(const s8v*)&As[(kq + rb + i * 16 + r16) * 8];
        bfr[g][i] = *(const s8v*)&Bs[(kq + cw + i * 16 + r16) * 8];
      }
    }
#pragma unroll
    for (int g = 0; g < 2; ++g)
#pragma unroll
      for (int mi = 0; mi < 4; ++mi)
#pragma unroll
        for (int ni = 0; ni < 4; ++ni)
          acc[mi][ni] = __builtin_amdgcn_mfma_f32_16x16x32_bf16(
              af[g][mi], bfr[g][ni], acc[mi][ni], 0, 0, 0);
  }

  float* sc = kh ? sc1 : sc0;
#pragma unroll
  for (int mi = 0; mi < 4; ++mi) {
#pragma unroll
    for (int ni = 0; ni < 4; ++ni) {
      int col = n0 + cw + ni * 16 + r16;
      float cnv = kh ? 0.f : cn[col];
#pragma unroll
      for (int r = 0; r < 4; ++r) {
        int row = m0 + rb + mi * 16 + q * 4 + r;
        sc[(size_t)row * 8192 + col] = -2.f * acc[mi][ni][r] + cnv;
      }
    }
  }
}

// ---------------- argmin with exact fp32 recheck (wave-parallel) ----------
// Margin is STATISTICAL, not worst-case: per-score bf16 error sigma
// ~2^-9*c_max*||z||_2 (~1e-5); margin = ||z||_2/131072 + 1e-4 (~3.4e-4)
// is >25 sigma on score differences while typical 1st-2nd gap is ~1.6e-3.
// (R3's worst-case margin 0.016 exceeded the whole score spread -> 128
// candidates/row -> full codebook re-read, 1318 us.)
__global__ void k_argmin(const float* __restrict__ s0, const float* __restrict__ s1,
                         const float* __restrict__ z_e, const float* __restrict__ cb,
                         const float* __restrict__ zn2, const float* __restrict__ cn,
                         int* __restrict__ idx, float* __restrict__ counts) {
  __shared__ float red[256];
  __shared__ int cand[128];
  __shared__ float cval[128];
  __shared__ int ccnt;
  int b = blockIdx.x, tid = threadIdx.x;
  const float* r0 = s0 + (size_t)b * 8192;
  const float* r1 = s1 + (size_t)b * 8192;
  float mn = 1e30f;
  for (int j4 = tid; j4 < 2048; j4 += 256) {
    float4 a = *(const float4*)&r0[j4 * 4];
    float4 c = *(const float4*)&r1[j4 * 4];
    mn = fminf(mn, fminf(fminf(a.x + c.x, a.y + c.y), fminf(a.z + c.z, a.w + c.w)));
  }
  red[tid] = mn;
  __syncthreads();
  for (int st = 128; st > 0; st >>= 1) {
    if (tid < st) red[tid] = fminf(red[tid], red[tid + st]);
    __syncthreads();
  }
  float minv = red[0];
  float margin = sqrtf(zn2[b]) * (1.0f / 131072.0f) + 1e-4f;
  if (tid == 0) ccnt = 0;
  __syncthreads();
  float thr = minv + margin;
  for (int j4 = tid; j4 < 2048; j4 += 256) {
    float4 a = *(const float4*)&r0[j4 * 4];
    float4 c = *(const float4*)&r1[j4 * 4];
    float v[4] = {a.x + c.x, a.y + c.y, a.z + c.z, a.w + c.w};
#pragma unroll
    for (int u = 0; u < 4; ++u) {
      if (v[u] <= thr) {
        int p = atomicAdd(&ccnt, 1);
        if (p < 128) cand[p] = j4 * 4 + u;
      }
    }
  }
  __syncthreads();
  int nc = min(ccnt, 128);
  int wave = tid >> 6, lane = tid & 63;
  const float* zr = z_e + (size_t)b * 8320;
  float zn = zn2[b];
  for (int ci = wave; ci < nc; ci += 4) {
    int j = cand[ci];
    const float* cr = cb + (size_t)j * 8320;
    float dp = 0.f;
    for (int k4 = lane; k4 < 2080; k4 += 64) {
      float4 zv = *(const float4*)&zr[k4 * 4];
      float4 cv = *(const float4*)&cr[k4 * 4];
      dp = fmaf(zv.x, cv.x, dp);
      dp = fmaf(zv.y, cv.y, dp);
      dp = fmaf(zv.z, cv.z, dp);
      dp = fmaf(zv.w, cv.w, dp);
    }
    for (int off = 32; off > 0; off >>= 1) dp += __shfl_down(dp, off);
    // replicate reference rounding: fl(fl(zn+cn) - fl(2*dot))
    if (lane == 0)
      cval[ci] = __fsub_rn(__fadd_rn(zn, cn[j]), __fmul_rn(2.f, dp));
  }
  __syncthreads();
  if (tid == 0) {
    float bv = 1e30f;
    int bj = 0x7fffffff;
    for (int ci = 0; ci < nc; ++ci) {
      float v = cval[ci];
      int j = cand[ci];
      if (v < bv || (v == bv && j < bj)) { bv = v; bj = j; }
    }
    idx[b] = bj;
    atomicAdd(&counts[bj], 1.0f);
  }
}

// ---------------- gather zq + emb loss partial ----------------
__global__ void k_gather(const float* __restrict__ cb, const float* __restrict__ z_e,
                         const int* __restrict__ idx, float* __restrict__ zq,
                         float* __restrict__ emb_acc) {
  __shared__ float red[256];
  int b = blockIdx.x, tid = threadIdx.x;
  int j = idx[b];
  const float* cr = cb + (size_t)j * 8320;
  const float* zr = z_e + (size_t)b * 8320;
  float* q = zq + (size_t)b * 8320;
  float part = 0.f;
  for (int k = tid; k < 8320; k += 256) {
    float c = cr[k];
    float d = c - zr[k];
    q[k] = c;
    part += d * d;
  }
  red[tid] = part;
  __syncthreads();
  for (int st = 128; st > 0; st >>= 1) {
    if (tid < st) red[tid] += red[tid + st];
    __syncthreads();
  }
  if (tid == 0) atomicAdd(emb_acc, red[0]);
}

// ---------------- deconv2 -> x_hat ----------------
__global__ void k_dec2(const float* __restrict__ hd, const float* __restrict__ w,
                       const float* __restrict__ bias, float* __restrict__ out) {
  int id = blockIdx.x * 256 + threadIdx.x;
  if (id >= 512 * 260) return;
  int b = id / 260, t = id % 260;
  int u = t >> 1;
  const float* hb = hd + (size_t)b * 8320;
  float acc = bias[0];
  if (t & 1) {
    bool ok = (u + 1 < 130);
    for (int i = 0; i < 64; ++i) {
      acc = fmaf(hb[i * 130 + u], w[i * 4 + 2], acc);
      if (ok) acc = fmaf(hb[i * 130 + u + 1], w[i * 4 + 0], acc);
    }
  } else {
    bool ok = (u >= 1);
    for (int i = 0; i < 64; ++i) {
      if (ok) acc = fmaf(hb[i * 130 + u - 1], w[i * 4 + 3], acc);
      acc = fmaf(hb[i * 130 + u], w[i * 4 + 1], acc);
    }
  }
  out[OUT_XHAT + id] = acc;
}

// ---------------- mt head (float4 loads) ----------------
__global__ void k_mt(const float* __restrict__ z_e, const float* __restrict__ mtw,
                     const float* __restrict__ mtb, float* __restrict__ out) {
  __shared__ float red[64];
  int b = blockIdx.x, tid = threadIdx.x;
  int wave = tid >> 6, lane = tid & 63;
  const float* zr = z_e + (size_t)b * 8320;
  float acc[16];
#pragma unroll
  for (int n = 0; n < 16; ++n) acc[n] = 0.f;
  for (int k4 = tid; k4 < 1040; k4 += 256) {
    float4 zv = *(const float4*)&zr[k4 * 4];
#pragma unroll
    for (int n = 0; n < 16; ++n) {
      float4 wv = *(const float4*)&mtw[n * 4160 + k4 * 4];
      float a = acc[n];
      a = fmaf(zv.x, wv.x, a);
      a = fmaf(zv.y, wv.y, a);
      a = fmaf(zv.z, wv.z, a);
      a = fmaf(zv.w, wv.w, a);
      acc[n] = a;
    }
  }
#pragma unroll
  for (int n = 0; n < 16; ++n) {
    float v = acc[n];
    for (int off = 32; off > 0; off >>= 1) v += __shfl_down(v, off);
    if (lane == 0) red[n * 4 + wave] = v;
  }
  __syncthreads();
  if (tid < 16) {
    float s = red[tid * 4] + red[tid * 4 + 1] + red[tid * 4 + 2] + red[tid * 4 + 3];
    out[OUT_MT + b * 16 + tid] = s + mtb[tid];
  }
}

// ---------------- adv layer 1 (tiled fp32 GEMM, K-split 10, atomic acc) ----
__global__ __launch_bounds__(256) void k_adv1(const float* __restrict__ z_e,
                                              const float* __restrict__ w1,
                                              float* __restrict__ a1) {
  __shared__ float At[32 * 64];
  __shared__ float Bt[32 * 64];
  int bid = blockIdx.x;
  int ksp = bid % 10;
  int nt = (bid / 10) & 3;
  int mt = bid / 40;
  int tid = threadIdx.x;
  int m0 = mt * 64, n0 = nt * 64, kb = ksp * 416;
  int tm = (tid & 15) * 4, tn = (tid >> 4) * 4;
  int sr = tid & 63, sj = (tid >> 6) * 8;
  const float* za = z_e + (size_t)(m0 + sr) * 8320 + 4160 + kb + sj;
  const float* wb = w1 + (size_t)(n0 + sr) * 4160 + kb + sj;
  float acc[4][4];
#pragma unroll
  for (int i = 0; i < 4; ++i)
#pragma unroll
    for (int j = 0; j < 4; ++j) acc[i][j] = 0.f;
  for (int k0 = 0; k0 < 416; k0 += 32) {
    float4 av0 = *(const float4*)(za + k0);
    float4 av1 = *(const float4*)(za + k0 + 4);
    float4 bv0 = *(const float4*)(wb + k0);
    float4 bv1 = *(const float4*)(wb + k0 + 4);
    __syncthreads();
    At[(sj + 0) * 64 + sr] = av0.x; At[(sj + 1) * 64 + sr] = av0.y;
    At[(sj + 2) * 64 + sr] = av0.z; At[(sj + 3) * 64 + sr] = av0.w;
    At[(sj + 4) * 64 + sr] = av1.x; At[(sj + 5) * 64 + sr] = av1.y;
    At[(sj + 6) * 64 + sr] = av1.z; At[(sj + 7) * 64 + sr] = av1.w;
    Bt[(sj + 0) * 64 + sr] = bv0.x; Bt[(sj + 1) * 64 + sr] = bv0.y;
    Bt[(sj + 2) * 64 + sr] = bv0.z; Bt[(sj + 3) * 64 + sr] = bv0.w;
    Bt[(sj + 4) * 64 + sr] = bv1.x; Bt[(sj + 5) * 64 + sr] = bv1.y;
    Bt[(sj + 6) * 64 + sr] = bv1.z; Bt[(sj + 7) * 64 + sr] = bv1.w;
    __syncthreads();
#pragma unroll
    for (int kk = 0; kk < 32; ++kk) {
      float4 aa = *(const float4*)&At[kk * 64 + tm];
      float4 bb = *(const float4*)&Bt[kk * 64 + tn];
      acc[0][0] = fmaf(aa.x, bb.x, acc[0][0]); acc[0][1] = fmaf(aa.x, bb.y, acc[0][1]);
      acc[0][2] = fmaf(aa.x, bb.z, acc[0][2]); acc[0][3] = fmaf(aa.x, bb.w, acc[0][3]);
      acc[1][0] = fmaf(aa.y, bb.x, acc[1][0]); acc[1][1] = fmaf(aa.y, bb.y, acc[1][1]);
      acc[1][2] = fmaf(aa.y, bb.z, acc[1][2]); acc[1][3] = fmaf(aa.y, bb.w, acc[1][3]);
      acc[2][0] = fmaf(aa.z, bb.x, acc[2][0]); acc[2][1] = fmaf(aa.z, bb.y, acc[2][1]);
      acc[2][2] = fmaf(aa.z, bb.z, acc[2][2]); acc[2][3] = fmaf(aa.z, bb.w, acc[2][3]);
      acc[3][0] = fmaf(aa.w, bb.x, acc[3][0]); acc[3][1] = fmaf(aa.w, bb.y, acc[3][1]);
      acc[3][2] = fmaf(aa.w, bb.z, acc[3][2]); acc[3][3] = fmaf(aa.w, bb.w, acc[3][3]);
    }
  }
#pragma unroll
  for (int i = 0; i < 4; ++i)
#pragma unroll
    for (int j = 0; j < 4; ++j)
      atomicAdd(&a1[(size_t)(m0 + tm + i) * 256 + n0 + tn + j], acc[i][j]);
}

// ---------------- adv layers 2+3 fused ----------------
__global__ void k_adv23(const float* __restrict__ a1raw, const float* __restrict__ b1,
                        const float* __restrict__ w2t, const float* __restrict__ b2,
                        const float* __restrict__ w3, const float* __restrict__ b3,
                        float* __restrict__ out) {
  __shared__ float s1[256];
  __shared__ float s2[128];
  int b = blockIdx.x, tid = threadIdx.x;
  s1[tid] = fmaxf(a1raw[(size_t)b * 256 + tid] + b1[tid], 0.f);
  __syncthreads();
  if (tid < 128) {
    float acc = b2[tid];
    for (int k = 0; k < 256; ++k) acc = fmaf(s1[k], w2t[k * 128 + tid], acc);
    s2[tid] = fmaxf(acc, 0.f);
  }
  __syncthreads();
  if (tid < 16) {
    float acc = b3[tid];
    for (int k = 0; k < 128; ++k) acc = fmaf(s2[k], w3[tid * 128 + k], acc);
    out[OUT_ADV + b * 16 + tid] = acc;
  }
}

// ---------------- finalize: emb loss + perplexity ----------------
__global__ void k_fin(const float* __restrict__ counts, const float* __restrict__ emb_acc,
                      const float* __restrict__ beta_p, float* __restrict__ out) {
  __shared__ float red[256];
  int tid = threadIdx.x;
  float part = 0.f;
  for (int j = tid; j < 8192; j += 256) {
    float e = counts[j] * (1.0f / 512.0f);
    part += e * logf(e + 1e-10f);
  }
  red[tid] = part;
  __syncthreads();
  for (int st = 128; st > 0; st >>= 1) {
    if (tid < st) red[tid] += red[tid + st];
    __syncthreads();
  }
  if (tid == 0) {
    out[OUT_PERP] = expf(-red[0]);
    out[0] = (1.f + beta_p[0]) * emb_acc[0] * (1.0f / 4259840.0f);
  }
}

extern "C" void kernel_launch(void* const* d_in, const int* in_sizes, int n_in,
                              void* d_out, int out_size, void* d_ws, size_t ws_size,
                              hipStream_t stream) {
  (void)in_sizes; (void)n_in; (void)out_size; (void)ws_size;
  const float* x   = (const float*)d_in[0];
  const float* cb  = (const float*)d_in[1];
  const float* c1w = (const float*)d_in[2];
  const float* c1b = (const float*)d_in[3];
  const float* c2w = (const float*)d_in[4];
  const float* c2b = (const float*)d_in[5];
  const float* d1w = (const float*)d_in[6];
  const float* d1b = (const float*)d_in[7];
  const float* d2w = (const float*)d_in[8];
  const float* d2b = (const float*)d_in[9];
  const float* mtw = (const float*)d_in[10];
  const float* mtb = (const float*)d_in[11];
  const float* aw1 = (const float*)d_in[12];
  const float* ab1 = (const float*)d_in[13];
  const float* aw2 = (const float*)d_in[14];
  const float* ab2 = (const float*)d_in[15];
  const float* aw3 = (const float*)d_in[16];
  const float* ab3 = (const float*)d_in[17];
  const float* beta = (const float*)d_in[18];
  float* out = (float*)d_out;
  float* W = (float*)d_ws;

  float* counts = W + WS_COUNTS;
  float* embac  = W + WS_EMB;
  float* a1buf  = W + WS_A1;
  float* cnbuf  = W + WS_CN;
  float* zn2    = W + WS_ZN2;
  float* zl1    = W + WS_ZL1;
  float* cbl1   = W + WS_CBL1;
  float* zebuf  = W + WS_ZE;
  float* sc0    = W + WS_SC0;
  float* sc1    = W + WS_SC1;
  float* zqbuf  = W + WS_ZQ;
  float* hdbuf  = W + WS_HD;
  float* w2t    = W + WS_W2T;
  float* We     = W + WS_WE;
  float* Wo     = W + WS_WO;
  float* w2ta   = W + WS_W2TA;
  int*   idxb   = (int*)(W + WS_IDX);
  short* zpk    = (short*)(W + WS_ZPK);
  short* cbt    = (short*)(W + WS_CBT);
  float* hbuf   = W + WS_H;   // aliases cbt region; dead before cbt written

  k_init<<<(WS_ZERO_N + 255) / 256, 256, 0, stream>>>(W);
  k_prep<<<128, 256, 0, stream>>>(c2w, d1w, aw2, w2t, We, Wo, w2ta);
  k_conv1<<<16640, 256, 0, stream>>>(x, c1w, c1b, hbuf);
  k_gemm_gather<128><<<520, 256, 0, stream>>>(hbuf, 64, 130, 2, 1, -1, w2t, c2b,
                                              zebuf, 65, 1, 0, 0);
  // pack z -> bf16 chunk-major + ||z||^2 + ||z||_1   (h now dead)
  k_packmat<<<8 * 130, 256, 0, stream>>>(zebuf, zpk, zn2, zl1, 512, 8);
  // pack codebook -> bf16 chunk-major + ||c||^2  (overwrites h region)
  k_packmat<<<128 * 130, 256, 0, stream>>>(cb, cbt, cnbuf, cbl1, 8192, 128);
  k_scores<<<512, 256, 0, stream>>>(cbt, zpk, cnbuf, sc0, sc1);
  k_argmin<<<512, 256, 0, stream>>>(sc0, sc1, zebuf, cb, zn2, cnbuf, idxb,
                                    counts);
  k_gather<<<512, 256, 0, stream>>>(cb, zebuf, idxb, zqbuf, embac);
  k_gemm_gather<64><<<520, 256, 0, stream>>>(zqbuf, 128, 65, 1, 0, -1, We, d1b,
                                             hdbuf, 130, 2, 0, 1);
  k_gemm_gather<64><<<520, 256, 0, stream>>>(zqbuf, 128, 65, 1, 0, 0, Wo, d1b,
                                             hdbuf, 130, 2, 1, 1);
  k_dec2<<<520, 256, 0, stream>>>(hdbuf, d2w, d2b, out);
  k_mt<<<512, 256, 0, stream>>>(zebuf, mtw, mtb, out);
  k_adv1<<<320, 256, 0, stream>>>(zebuf, aw1, a1buf);
  k_adv23<<<512, 256, 0, stream>>>(a1buf, ab1, w2ta, ab2, aw3, ab3, out);
  k_fin<<<1, 256, 0, stream>>>(counts, embac, beta, out);
}